// Round 1
// baseline (402.763 us; speedup 1.0000x reference)
//
#include <hip/hip_runtime.h>
#include <hip/hip_bf16.h>

typedef __attribute__((ext_vector_type(8))) short bf16x8;
typedef __attribute__((ext_vector_type(4))) float f32x4;

__device__ __forceinline__ void load_lds16(const void* g, void* l) {
    __builtin_amdgcn_global_load_lds(
        (const __attribute__((address_space(1))) unsigned int*)g,
        (__attribute__((address_space(3))) unsigned int*)l, 16, 0, 0);
}

// ---------------------------------------------------------------- prep kernels
__global__ void k_cvt_x(const float* __restrict__ x, __hip_bfloat16* __restrict__ xb, int n4) {
    for (int i = blockIdx.x * blockDim.x + threadIdx.x; i < n4; i += gridDim.x * blockDim.x) {
        float4 v = ((const float4*)x)[i];
        union { ushort4 u; __hip_bfloat16 h[4]; } o;
        o.h[0] = __float2bfloat16(v.x); o.h[1] = __float2bfloat16(v.y);
        o.h[2] = __float2bfloat16(v.z); o.h[3] = __float2bfloat16(v.w);
        ((ushort4*)xb)[i] = o.u;
    }
}

__global__ void k_prep_w(const float* __restrict__ qkv_w, const float* __restrict__ qkv_b,
                         const float* __restrict__ proj_w, const float* __restrict__ bias_table,
                         __hip_bfloat16* __restrict__ qwT, __hip_bfloat16* __restrict__ pwT,
                         float* __restrict__ qb_s, float* __restrict__ biasH) {
    const float scale = 0.17677669529663687f; // 32^-0.5
    int i = blockIdx.x * 256 + threadIdx.x;
    if (i < 768 * 256) {
        int nc = i >> 8, kc = i & 255;
        float v = qkv_w[kc * 768 + nc];
        if (nc < 256) v *= scale;
        qwT[i] = __float2bfloat16(v);
    } else if (i < 768 * 256 + 256 * 256) {
        int j = i - 768 * 256;
        int nc = j >> 8, kc = j & 255;
        pwT[j] = __float2bfloat16(proj_w[kc * 256 + nc]);
    } else if (i < 768 * 256 + 256 * 256 + 768) {
        int j = i - (768 * 256 + 256 * 256);
        qb_s[j] = qkv_b[j] * (j < 256 ? scale : 1.f);
    } else if (i < 768 * 256 + 256 * 256 + 768 + 8 * 2401) {
        int j = i - (768 * 256 + 256 * 256 + 768);
        int h = j / 2401, r = j % 2401;
        int n = r / 49, m = r % 49;
        int i1 = n / 7, j1 = n % 7, i2 = m / 7, j2 = m % 7;
        int rpi = (i1 - i2 + 6) * 13 + (j1 - j2 + 6);
        biasH[j] = bias_table[rpi * 8 + h];
    }
}

// ---------------------------------------------------------------- GEMM: C = A @ BT^T + bias
// A [M][K] bf16 row-major, BT [N][K] bf16 row-major (i.e. B transposed).
// 128x128 tile, BK=64, 4 waves, double-buffered global_load_lds, XOR-swizzled via source.
template <bool OUT_BF16>
__global__ __launch_bounds__(256, 2)
void gemm_bt(const __hip_bfloat16* __restrict__ A,
             const __hip_bfloat16* __restrict__ BT,
             const float* __restrict__ bias,
             void* __restrict__ Cout,
             int M, int N, int K) {
    __shared__ alignas(16) __hip_bfloat16 sA[2][128][64];
    __shared__ alignas(16) __hip_bfloat16 sB[2][128][64];
    const int bn = blockIdx.x, bm = blockIdx.y;
    const int tid = threadIdx.x, wid = tid >> 6, lane = tid & 63;
    const int g = lane >> 4, c0 = lane & 15;
    const int r8 = lane >> 3;
    const int sl = (lane & 7) ^ r8;            // swizzled source slot (inverse of read XOR)
    const int wrow = (wid >> 1) * 64, wcol = (wid & 1) * 64;
    const __hip_bfloat16* Abase = A + (size_t)bm * 128 * K;
    const __hip_bfloat16* Bbase = BT + (size_t)bn * 128 * K;
    const int KT = K >> 6;

    f32x4 acc[4][4];
#pragma unroll
    for (int i = 0; i < 4; ++i)
#pragma unroll
        for (int j = 0; j < 4; ++j)
#pragma unroll
            for (int r = 0; r < 4; ++r) acc[i][j][r] = 0.f;

    auto stage = [&](int buf, int kt) {
        const __hip_bfloat16* Ak = Abase + kt * 64;
        const __hip_bfloat16* Bk = Bbase + kt * 64;
        char* la = (char*)&sA[buf][0][0];
        char* lb = (char*)&sB[buf][0][0];
#pragma unroll
        for (int i = 0; i < 4; ++i) {
            int chunk = wid * 4 + i;           // 16 chunks of 1024B per operand
            int row = chunk * 8 + r8;          // 0..127
            load_lds16(Ak + (size_t)row * K + sl * 8, la + chunk * 1024);
            load_lds16(Bk + (size_t)row * K + sl * 8, lb + chunk * 1024);
        }
    };

    stage(0, 0);
    __syncthreads();
    for (int kt = 0; kt < KT; ++kt) {
        int cur = kt & 1;
        if (kt + 1 < KT) stage(cur ^ 1, kt + 1);
        const char* la = (const char*)&sA[cur][0][0];
        const char* lb = (const char*)&sB[cur][0][0];
#pragma unroll
        for (int ks = 0; ks < 2; ++ks) {
            bf16x8 af[4], bfr[4];
            int sbyte = ((ks * 4 + g) ^ (c0 & 7)) * 16;  // read-side XOR swizzle
#pragma unroll
            for (int t = 0; t < 4; ++t) {
                int ra = wrow + t * 16 + c0;
                af[t] = *(const bf16x8*)(la + ra * 128 + sbyte);
                int rb = wcol + t * 16 + c0;
                bfr[t] = *(const bf16x8*)(lb + rb * 128 + sbyte);
            }
#pragma unroll
            for (int rt = 0; rt < 4; ++rt)
#pragma unroll
                for (int ct = 0; ct < 4; ++ct)
                    acc[rt][ct] = __builtin_amdgcn_mfma_f32_16x16x32_bf16(
                        af[rt], bfr[ct], acc[rt][ct], 0, 0, 0);
        }
        __syncthreads();
    }

    float bv[4];
#pragma unroll
    for (int ct = 0; ct < 4; ++ct) bv[ct] = bias[bn * 128 + wcol + ct * 16 + c0];
#pragma unroll
    for (int rt = 0; rt < 4; ++rt) {
#pragma unroll
        for (int ct = 0; ct < 4; ++ct) {
#pragma unroll
            for (int reg = 0; reg < 4; ++reg) {
                int row = bm * 128 + wrow + rt * 16 + g * 4 + reg;
                int col = bn * 128 + wcol + ct * 16 + c0;
                float v = acc[rt][ct][reg] + bv[ct];
                if (OUT_BF16)
                    ((__hip_bfloat16*)Cout)[(size_t)row * N + col] = __float2bfloat16(v);
                else
                    ((float*)Cout)[(size_t)row * N + col] = v;
            }
        }
    }
}

// ---------------------------------------------------------------- fused window attention
// one wave per (window b, head h). qkv rows: [b*49+n][768], q=0..255 (pre-scaled), k=256.., v=512..
__global__ __launch_bounds__(64)
void attn_win(const __hip_bfloat16* __restrict__ qkv,
              const float* __restrict__ mask,   // [64][49][49]
              const float* __restrict__ biasH,  // [8][49][49]
              __hip_bfloat16* __restrict__ attout) {
    __shared__ alignas(16) __hip_bfloat16 vt[32][72];  // V^T: vt[c][m], stride 144B (9*16)
    __shared__ alignas(16) __hip_bfloat16 pl[64][64];  // P, XOR-swizzled rows
    const int bh = blockIdx.x;
    const int b = bh >> 3, h = bh & 7;
    const int lane = threadIdx.x & 63, g = lane >> 4, c0 = lane & 15;
    const __hip_bfloat16* qb = qkv + (size_t)b * 49 * 768 + h * 32;

    // zero V^T pad rows m=49..63
    for (int i = lane; i < 32 * 15; i += 64) {
        int c = i / 15, m = 49 + i % 15;
        vt[c][m] = __float2bfloat16(0.f);
    }
    // stage V transposed (coalesced 4B global reads, scalar LDS writes)
    for (int i = lane; i < 784; i += 64) {
        int m = i >> 4, c2 = (i & 15) * 2;
        ushort2 v = *(const ushort2*)(qb + (size_t)m * 768 + 512 + c2);
        *(unsigned short*)&vt[c2][m] = v.x;
        *(unsigned short*)&vt[c2 + 1][m] = v.y;
    }

    const bf16x8 z8 = {};
    bf16x8 kf[4];
#pragma unroll
    for (int ct = 0; ct < 4; ++ct) {
        int m = ct * 16 + c0;
        kf[ct] = (m < 49) ? *(const bf16x8*)(qb + (size_t)m * 768 + 256 + g * 8) : z8;
    }
    __syncthreads();

    const float* mrow = mask + (size_t)(b & 63) * 2401;
    const float* brow = biasH + (size_t)h * 2401;
    const f32x4 zf = {0.f, 0.f, 0.f, 0.f};

#pragma unroll
    for (int rt = 0; rt < 4; ++rt) {
        int nA = rt * 16 + c0;
        bf16x8 qf = (nA < 49) ? *(const bf16x8*)(qb + (size_t)nA * 768 + g * 8) : z8;
        f32x4 s[4];
#pragma unroll
        for (int ct = 0; ct < 4; ++ct)
            s[ct] = __builtin_amdgcn_mfma_f32_16x16x32_bf16(qf, kf[ct], zf, 0, 0, 0);
        // rows n = rt*16 + 4g + reg ; cols m = ct*16 + c0
#pragma unroll
        for (int reg = 0; reg < 4; ++reg) {
            int n = rt * 16 + 4 * g + reg;
            int nc = n < 49 ? n : 48;
            const float* br = brow + nc * 49;
            const float* mr = mrow + nc * 49;
#pragma unroll
            for (int ct = 0; ct < 4; ++ct) {
                int m = ct * 16 + c0;
                float v = s[ct][reg];
                v = (m < 49) ? v + br[m] + mr[m] : -1e30f;
                s[ct][reg] = v;
            }
            float mx = fmaxf(fmaxf(s[0][reg], s[1][reg]), fmaxf(s[2][reg], s[3][reg]));
            mx = fmaxf(mx, __shfl_xor(mx, 1));
            mx = fmaxf(mx, __shfl_xor(mx, 2));
            mx = fmaxf(mx, __shfl_xor(mx, 4));
            mx = fmaxf(mx, __shfl_xor(mx, 8));
            float sum = 0.f;
#pragma unroll
            for (int ct = 0; ct < 4; ++ct) {
                float e = __expf(s[ct][reg] - mx);
                s[ct][reg] = e;
                sum += e;
            }
            sum += __shfl_xor(sum, 1);
            sum += __shfl_xor(sum, 2);
            sum += __shfl_xor(sum, 4);
            sum += __shfl_xor(sum, 8);
            float inv = 1.f / sum;
#pragma unroll
            for (int ct = 0; ct < 4; ++ct) {
                int m = ct * 16 + c0;
                int byte = (n * 128 + m * 2) ^ ((n & 7) << 4);
                *(__hip_bfloat16*)((char*)&pl[0][0] + byte) = __float2bfloat16(s[ct][reg] * inv);
            }
        }
    }
    __syncthreads();

    f32x4 o[4][2];
#pragma unroll
    for (int rt = 0; rt < 4; ++rt)
#pragma unroll
        for (int ci = 0; ci < 2; ++ci)
#pragma unroll
            for (int r = 0; r < 4; ++r) o[rt][ci][r] = 0.f;
#pragma unroll
    for (int kt = 0; kt < 2; ++kt) {
        bf16x8 pa[4], vb[2];
#pragma unroll
        for (int rt = 0; rt < 4; ++rt) {
            int row = rt * 16 + c0;
            int byte = row * 128 + (((kt * 4 + g) ^ (row & 7)) << 4);
            pa[rt] = *(const bf16x8*)((const char*)&pl[0][0] + byte);
        }
#pragma unroll
        for (int ci = 0; ci < 2; ++ci)
            vb[ci] = *(const bf16x8*)(&vt[ci * 16 + c0][kt * 32 + g * 8]);
#pragma unroll
        for (int rt = 0; rt < 4; ++rt)
#pragma unroll
            for (int ci = 0; ci < 2; ++ci)
                o[rt][ci] = __builtin_amdgcn_mfma_f32_16x16x32_bf16(pa[rt], vb[ci], o[rt][ci], 0, 0, 0);
    }
    __hip_bfloat16* ob = attout + (size_t)b * 49 * 256 + h * 32;
#pragma unroll
    for (int rt = 0; rt < 4; ++rt) {
#pragma unroll
        for (int reg = 0; reg < 4; ++reg) {
            int n = rt * 16 + 4 * g + reg;
            if (n < 49) {
#pragma unroll
                for (int ci = 0; ci < 2; ++ci)
                    ob[(size_t)n * 256 + ci * 16 + c0] = __float2bfloat16(o[rt][ci][reg]);
            }
        }
    }
}

// ---------------------------------------------------------------- host
extern "C" void kernel_launch(void* const* d_in, const int* in_sizes, int n_in,
                              void* d_out, int out_size, void* d_ws, size_t ws_size,
                              hipStream_t stream) {
    const float* x          = (const float*)d_in[0];
    const float* mask       = (const float*)d_in[1];
    const float* qkv_w      = (const float*)d_in[2];
    const float* qkv_b      = (const float*)d_in[3];
    const float* proj_w     = (const float*)d_in[4];
    const float* proj_b     = (const float*)d_in[5];
    const float* bias_table = (const float*)d_in[6];

    const int C = 256, N3 = 768, NN = 49;
    const int M  = in_sizes[0] / C;  // 100352
    const int B_ = M / NN;           // 2048

    char* ws = (char*)d_ws;
    __hip_bfloat16* qkv_ws = (__hip_bfloat16*)ws;                   // [M][768] bf16
    size_t off = (size_t)M * N3 * 2;
    __hip_bfloat16* xb  = (__hip_bfloat16*)(ws + off);              // [M][256] bf16
    __hip_bfloat16* att = xb;                                       // aliased: x dead after qkv GEMM
    off += (size_t)M * C * 2;
    __hip_bfloat16* qwT = (__hip_bfloat16*)(ws + off); off += (size_t)N3 * C * 2;  // [768][256]
    __hip_bfloat16* pwT = (__hip_bfloat16*)(ws + off); off += (size_t)C * C * 2;   // [256][256]
    float* qb_s  = (float*)(ws + off); off += (size_t)N3 * 4;
    float* biasH = (float*)(ws + off); off += (size_t)8 * 2401 * 4;

    int n4 = (int)((size_t)M * C / 4);
    k_cvt_x<<<2048, 256, 0, stream>>>(x, xb, n4);
    int prep_total = 768 * 256 + 256 * 256 + 768 + 8 * 2401;
    k_prep_w<<<(prep_total + 255) / 256, 256, 0, stream>>>(qkv_w, qkv_b, proj_w, bias_table,
                                                           qwT, pwT, qb_s, biasH);
    gemm_bt<true><<<dim3(N3 / 128, M / 128), 256, 0, stream>>>(xb, qwT, qb_s, qkv_ws, M, N3, C);
    attn_win<<<B_ * 8, 64, 0, stream>>>(qkv_ws, mask, biasH, att);
    gemm_bt<false><<<dim3(C / 128, M / 128), 256, 0, stream>>>(att, pwT, proj_b, d_out, M, C, C);
}

// Round 3
// 362.718 us; speedup vs baseline: 1.1104x; 1.1104x over previous
//
#include <hip/hip_runtime.h>
#include <hip/hip_bf16.h>

typedef __attribute__((ext_vector_type(8))) short bf16x8;
typedef __attribute__((ext_vector_type(4))) float f32x4;

__device__ __forceinline__ void load_lds16(const void* g, void* l) {
    __builtin_amdgcn_global_load_lds(
        (const __attribute__((address_space(1))) unsigned int*)g,
        (__attribute__((address_space(3))) unsigned int*)l, 16, 0, 0);
}

// ---------------------------------------------------------------- prep kernels
__global__ void k_cvt_x(const float* __restrict__ x, __hip_bfloat16* __restrict__ xb, int n4) {
    for (int i = blockIdx.x * blockDim.x + threadIdx.x; i < n4; i += gridDim.x * blockDim.x) {
        float4 v = ((const float4*)x)[i];
        union { ushort4 u; __hip_bfloat16 h[4]; } o;
        o.h[0] = __float2bfloat16(v.x); o.h[1] = __float2bfloat16(v.y);
        o.h[2] = __float2bfloat16(v.z); o.h[3] = __float2bfloat16(v.w);
        ((ushort4*)xb)[i] = o.u;
    }
}

// one merged prep kernel: weight transposes/cvt, scaled bias, and the combined
// (rel-pos bias + mask) table pre-laid-out in MFMA C-fragment order:
// cbt[w][h][rt][ct][lane] = f32x4 over reg, with -1e30 baked into m>=49 pad.
__global__ void k_prep(const float* __restrict__ qkv_w, const float* __restrict__ qkv_b,
                       const float* __restrict__ proj_w, const float* __restrict__ bias_table,
                       const float* __restrict__ mask,
                       __hip_bfloat16* __restrict__ qwT, __hip_bfloat16* __restrict__ pwT,
                       float* __restrict__ qb_s, float* __restrict__ cbt) {
    const float scale = 0.17677669529663687f; // 32^-0.5
    const int P1 = 768 * 256, P2 = P1 + 256 * 256, P3 = P2 + 768, P4 = P3 + 64 * 8 * 4 * 4 * 64;
    int i = blockIdx.x * 256 + threadIdx.x;
    if (i < P1) {
        int nc = i >> 8, kc = i & 255;
        float v = qkv_w[kc * 768 + nc];
        if (nc < 256) v *= scale;
        qwT[i] = __float2bfloat16(v);
    } else if (i < P2) {
        int j = i - P1;
        int nc = j >> 8, kc = j & 255;
        pwT[j] = __float2bfloat16(proj_w[kc * 256 + nc]);
    } else if (i < P3) {
        int j = i - P2;
        qb_s[j] = qkv_b[j] * (j < 256 ? scale : 1.f);
    } else if (i < P4) {
        int j = i - P3;                       // [w][h][rt][ct][lane]
        int w = j >> 13;
        int h = (j >> 10) & 7;
        int rt = (j >> 8) & 3;
        int ct = (j >> 6) & 3;
        int lane = j & 63;
        int m = ct * 16 + (lane & 15);
        f32x4 v;
#pragma unroll
        for (int reg = 0; reg < 4; ++reg) {
            int n = rt * 16 + 4 * (lane >> 4) + reg;
            float val;
            if (m >= 49) val = -1e30f;
            else if (n >= 49) val = 0.f;
            else {
                int i1 = n / 7, j1 = n % 7, i2 = m / 7, j2 = m % 7;
                int rpi = (i1 - i2 + 6) * 13 + (j1 - j2 + 6);
                val = bias_table[rpi * 8 + h] + mask[(w * 49 + n) * 49 + m];
            }
            v[reg] = val;
        }
        ((f32x4*)cbt)[j] = v;
    }
}

// ---------------------------------------------------------------- GEMM: C = A @ BT^T + bias
template <bool OUT_BF16>
__global__ __launch_bounds__(256, 2)
void gemm_bt(const __hip_bfloat16* __restrict__ A,
             const __hip_bfloat16* __restrict__ BT,
             const float* __restrict__ bias,
             void* __restrict__ Cout,
             int M, int N, int K, int gridN) {
    __shared__ alignas(16) __hip_bfloat16 sA[2][128][64];
    __shared__ alignas(16) __hip_bfloat16 sB[2][128][64];
    // bijective XCD swizzle (nwg % 8 == 0 for our grids)
    const int nwg = gridDim.x, bid = blockIdx.x;
    const int qq = nwg >> 3, rr = nwg & 7;
    const int xc = bid & 7, oo = bid >> 3;
    const int wg = (xc < rr ? xc * (qq + 1) : rr * (qq + 1) + (xc - rr) * qq) + oo;
    const int bm = wg / gridN, bn = wg % gridN;

    const int tid = threadIdx.x, wid = tid >> 6, lane = tid & 63;
    const int g = lane >> 4, c0 = lane & 15;
    const int r8 = lane >> 3;
    const int sl = (lane & 7) ^ r8;            // swizzled source slot (inverse of read XOR)
    const int wrow = (wid >> 1) * 64, wcol = (wid & 1) * 64;
    const __hip_bfloat16* Abase = A + (size_t)bm * 128 * K;
    const __hip_bfloat16* Bbase = BT + (size_t)bn * 128 * K;
    const int KT = K >> 6;

    f32x4 acc[4][4];
#pragma unroll
    for (int i = 0; i < 4; ++i)
#pragma unroll
        for (int j = 0; j < 4; ++j)
#pragma unroll
            for (int r = 0; r < 4; ++r) acc[i][j][r] = 0.f;

    auto stage = [&](int buf, int kt) {
        const __hip_bfloat16* Ak = Abase + kt * 64;
        const __hip_bfloat16* Bk = Bbase + kt * 64;
        char* la = (char*)&sA[buf][0][0];
        char* lb = (char*)&sB[buf][0][0];
#pragma unroll
        for (int i = 0; i < 4; ++i) {
            int chunk = wid * 4 + i;           // 16 chunks of 1024B per operand
            int row = chunk * 8 + r8;          // 0..127
            load_lds16(Ak + (size_t)row * K + sl * 8, la + chunk * 1024);
            load_lds16(Bk + (size_t)row * K + sl * 8, lb + chunk * 1024);
        }
    };

    stage(0, 0);
    __syncthreads();
    for (int kt = 0; kt < KT; ++kt) {
        int cur = kt & 1;
        if (kt + 1 < KT) stage(cur ^ 1, kt + 1);
        const char* la = (const char*)&sA[cur][0][0];
        const char* lb = (const char*)&sB[cur][0][0];
#pragma unroll
        for (int ks = 0; ks < 2; ++ks) {
            bf16x8 af[4], bfr[4];
            int sbyte = ((ks * 4 + g) ^ (c0 & 7)) * 16;  // read-side XOR swizzle
#pragma unroll
            for (int t = 0; t < 4; ++t) {
                int ra = wrow + t * 16 + c0;
                af[t] = *(const bf16x8*)(la + ra * 128 + sbyte);
                int rb = wcol + t * 16 + c0;
                bfr[t] = *(const bf16x8*)(lb + rb * 128 + sbyte);
            }
#pragma unroll
            for (int rt = 0; rt < 4; ++rt)
#pragma unroll
                for (int ct = 0; ct < 4; ++ct)
                    acc[rt][ct] = __builtin_amdgcn_mfma_f32_16x16x32_bf16(
                        af[rt], bfr[ct], acc[rt][ct], 0, 0, 0);
        }
        __syncthreads();
    }

    float bv[4];
#pragma unroll
    for (int ct = 0; ct < 4; ++ct) bv[ct] = bias[bn * 128 + wcol + ct * 16 + c0];
#pragma unroll
    for (int rt = 0; rt < 4; ++rt) {
#pragma unroll
        for (int ct = 0; ct < 4; ++ct) {
#pragma unroll
            for (int reg = 0; reg < 4; ++reg) {
                int row = bm * 128 + wrow + rt * 16 + g * 4 + reg;
                int col = bn * 128 + wcol + ct * 16 + c0;
                float v = acc[rt][ct][reg] + bv[ct];
                if (OUT_BF16)
                    ((__hip_bfloat16*)Cout)[(size_t)row * N + col] = __float2bfloat16(v);
                else
                    ((float*)Cout)[(size_t)row * N + col] = v;
            }
        }
    }
}

// ---------------------------------------------------------------- fused window attention
// one wave per (window b, head h); blockIdx remapped so 32 consecutive blocks
// share one cbt slice (same w=b&63, h).
__global__ __launch_bounds__(64)
void attn_win(const __hip_bfloat16* __restrict__ qkv,
              const float* __restrict__ cbt,    // [64][8][4][4][64][4] f32
              __hip_bfloat16* __restrict__ attout) {
    __shared__ alignas(16) __hip_bfloat16 vt[32][72];  // V^T: vt[c][m]
    __shared__ alignas(16) __hip_bfloat16 pl[52][64];  // P rows 0..51, XOR-swizzled
    const int blk = blockIdx.x;
    const int w = blk >> 8, h = (blk >> 5) & 7, rep = blk & 31;
    const int b = rep * 64 + w;
    const int lane = threadIdx.x & 63, g = lane >> 4, c0 = lane & 15;
    const __hip_bfloat16* qb = qkv + (size_t)b * 49 * 768 + h * 32;
    const bf16x8 z8 = {};

    // hoisted K and Q fragments
    bf16x8 kf[4], qf[4];
#pragma unroll
    for (int ct = 0; ct < 4; ++ct) {
        int m = ct * 16 + c0;
        kf[ct] = (m < 49) ? *(const bf16x8*)(qb + (size_t)m * 768 + 256 + g * 8) : z8;
    }
#pragma unroll
    for (int rt = 0; rt < 4; ++rt) {
        int n = rt * 16 + c0;
        qf[rt] = (n < 49) ? *(const bf16x8*)(qb + (size_t)n * 768 + g * 8) : z8;
    }

    // stage V transposed: 16B global loads, scalar transposed LDS writes
#pragma unroll
    for (int it = 0; it < 4; ++it) {
        int q = it * 64 + lane;
        int m = q >> 2, c8 = (q & 3) * 8;
        if (m < 49) {
            bf16x8 v8 = *(const bf16x8*)(qb + (size_t)m * 768 + 512 + c8);
#pragma unroll
            for (int j = 0; j < 8; ++j)
                *(short*)&vt[c8 + j][m] = v8[j];
        }
    }
    // zero pad rows m=49..63
    for (int i = lane; i < 32 * 15; i += 64) {
        int c = i / 15, m = 49 + i % 15;
        vt[c][m] = __float2bfloat16(0.f);
    }

    const f32x4* cbb = (const f32x4*)cbt + ((size_t)(w * 8 + h)) * 1024;
    const f32x4 zf = {0.f, 0.f, 0.f, 0.f};

#pragma unroll
    for (int rt = 0; rt < 4; ++rt) {
        f32x4 cb[4];
#pragma unroll
        for (int ct = 0; ct < 4; ++ct) cb[ct] = cbb[(rt * 4 + ct) * 64 + lane];
        f32x4 s[4];
        __builtin_amdgcn_s_setprio(1);
#pragma unroll
        for (int ct = 0; ct < 4; ++ct)
            s[ct] = __builtin_amdgcn_mfma_f32_16x16x32_bf16(qf[rt], kf[ct], zf, 0, 0, 0);
        __builtin_amdgcn_s_setprio(0);
#pragma unroll
        for (int ct = 0; ct < 4; ++ct)
#pragma unroll
            for (int reg = 0; reg < 4; ++reg) s[ct][reg] += cb[ct][reg];
        // rows n = rt*16 + 4g + reg ; cols m = ct*16 + c0
#pragma unroll
        for (int reg = 0; reg < 4; ++reg) {
            int n = rt * 16 + 4 * g + reg;
            float mx = fmaxf(fmaxf(s[0][reg], s[1][reg]), fmaxf(s[2][reg], s[3][reg]));
            mx = fmaxf(mx, __shfl_xor(mx, 1));
            mx = fmaxf(mx, __shfl_xor(mx, 2));
            mx = fmaxf(mx, __shfl_xor(mx, 4));
            mx = fmaxf(mx, __shfl_xor(mx, 8));
            float sum = 0.f;
#pragma unroll
            for (int ct = 0; ct < 4; ++ct) {
                float e = __expf(s[ct][reg] - mx);
                s[ct][reg] = e;
                sum += e;
            }
            sum += __shfl_xor(sum, 1);
            sum += __shfl_xor(sum, 2);
            sum += __shfl_xor(sum, 4);
            sum += __shfl_xor(sum, 8);
            float inv = 1.f / sum;
            if (n < 52) {
#pragma unroll
                for (int ct = 0; ct < 4; ++ct) {
                    int m = ct * 16 + c0;
                    int byte = (n * 128 + m * 2) ^ ((n & 7) << 4);
                    *(__hip_bfloat16*)((char*)&pl[0][0] + byte) = __float2bfloat16(s[ct][reg] * inv);
                }
            }
        }
    }
    __syncthreads();

    f32x4 o[4][2];
#pragma unroll
    for (int rt = 0; rt < 4; ++rt)
#pragma unroll
        for (int ci = 0; ci < 2; ++ci)
#pragma unroll
            for (int r = 0; r < 4; ++r) o[rt][ci][r] = 0.f;
#pragma unroll
    for (int kt = 0; kt < 2; ++kt) {
        bf16x8 pa[4], vb[2];
#pragma unroll
        for (int rt = 0; rt < 4; ++rt) {
            int row = rt * 16 + c0;
            int rc = row < 52 ? row : 51;       // rows >=49 feed discarded outputs
            int byte = rc * 128 + (((kt * 4 + g) ^ (rc & 7)) << 4);
            pa[rt] = *(const bf16x8*)((const char*)&pl[0][0] + byte);
        }
#pragma unroll
        for (int ci = 0; ci < 2; ++ci)
            vb[ci] = *(const bf16x8*)(&vt[ci * 16 + c0][kt * 32 + g * 8]);
        __builtin_amdgcn_s_setprio(1);
#pragma unroll
        for (int rt = 0; rt < 4; ++rt)
#pragma unroll
            for (int ci = 0; ci < 2; ++ci)
                o[rt][ci] = __builtin_amdgcn_mfma_f32_16x16x32_bf16(pa[rt], vb[ci], o[rt][ci], 0, 0, 0);
        __builtin_amdgcn_s_setprio(0);
    }
    __hip_bfloat16* ob = attout + (size_t)b * 49 * 256 + h * 32;
#pragma unroll
    for (int rt = 0; rt < 4; ++rt) {
#pragma unroll
        for (int reg = 0; reg < 4; ++reg) {
            int n = rt * 16 + 4 * g + reg;
            if (n < 49) {
#pragma unroll
                for (int ci = 0; ci < 2; ++ci)
                    ob[(size_t)n * 256 + ci * 16 + c0] = __float2bfloat16(o[rt][ci][reg]);
            }
        }
    }
}

// ---------------------------------------------------------------- host
extern "C" void kernel_launch(void* const* d_in, const int* in_sizes, int n_in,
                              void* d_out, int out_size, void* d_ws, size_t ws_size,
                              hipStream_t stream) {
    const float* x          = (const float*)d_in[0];
    const float* mask       = (const float*)d_in[1];
    const float* qkv_w      = (const float*)d_in[2];
    const float* qkv_b      = (const float*)d_in[3];
    const float* proj_w     = (const float*)d_in[4];
    const float* proj_b     = (const float*)d_in[5];
    const float* bias_table = (const float*)d_in[6];

    const int C = 256, N3 = 768, NN = 49;
    const int M  = in_sizes[0] / C;  // 100352
    const int B_ = M / NN;           // 2048

    char* ws = (char*)d_ws;
    __hip_bfloat16* qkv_ws = (__hip_bfloat16*)ws;                   // [M][768] bf16
    size_t off = (size_t)M * N3 * 2;
    __hip_bfloat16* xb  = (__hip_bfloat16*)(ws + off);              // [M][256] bf16
    __hip_bfloat16* att = xb;                                       // aliased: x dead after qkv GEMM
    off += (size_t)M * C * 2;
    __hip_bfloat16* qwT = (__hip_bfloat16*)(ws + off); off += (size_t)N3 * C * 2;  // [768][256]
    __hip_bfloat16* pwT = (__hip_bfloat16*)(ws + off); off += (size_t)C * C * 2;   // [256][256]
    float* qb_s = (float*)(ws + off); off += (size_t)N3 * 4;
    float* cbt  = (float*)(ws + off); off += (size_t)64 * 8 * 4096 * 4;            // 8 MB

    int n4 = (int)((size_t)M * C / 4);
    k_cvt_x<<<2048, 256, 0, stream>>>(x, xb, n4);
    int prep_total = 768 * 256 + 256 * 256 + 768 + 64 * 8 * 4 * 4 * 64;
    k_prep<<<(prep_total + 255) / 256, 256, 0, stream>>>(qkv_w, qkv_b, proj_w, bias_table, mask,
                                                         qwT, pwT, qb_s, cbt);
    gemm_bt<true><<<(N3 / 128) * (M / 128), 256, 0, stream>>>(xb, qwT, qb_s, qkv_ws, M, N3, C, N3 / 128);
    attn_win<<<B_ * 8, 64, 0, stream>>>(qkv_ws, cbt, att);
    gemm_bt<false><<<(C / 128) * (M / 128), 256, 0, stream>>>(att, pwT, proj_b, d_out, M, C, C, C / 128);
}